// Round 13
// baseline (9568.161 us; speedup 1.0000x reference)
//
#include <hip/hip_runtime.h>
#include <hip/hip_fp16.h>
#include <hip/hip_cooperative_groups.h>
#include <stdint.h>

#define TIME_STEPS 4096
#define DIM        2048
#define NBLK       256    // grid (co-resident: 1 block/CU)
#define NTH        512    // 8 waves per block
#define NWORK      32     // worker blocks (one XCD's worth of CUs)
#define WVB        8      // waves per worker block
#define RPW        8      // rows per wave: 256 waves x 8 = 2048

typedef uint32_t u32x4 __attribute__((ext_vector_type(4)));
typedef _Float16 h2f16 __attribute__((ext_vector_type(2)));

// actbuf entry: u32 = (tag16<<16)|fp16bits(act); slot t%NSLOT holds gen t
// (tag=t+1). Validity: min over dwords >= tag<<16 — detection embedded in
// the data (aggregate gates serialize: r10/r11).
// Key r13 changes: (1) x inputs batch-prefetched 16 steps ahead into
// registers (one ds_bpermute/step to distribute) so NO per-step HBM load
// shares vmcnt with the poll; (2) early-out poll — only stale lanes reload.
// Workers elected onto ONE XCD: producer/consumer sc1 ops meet in one L2.
// d_ws: ring | progress[NWORK] | xccmap[NBLK]

__device__ __forceinline__ uint32_t umin32(uint32_t a, uint32_t b) { return a < b ? a : b; }

__device__ __forceinline__ float dot2f(uint32_t packed, h2f16 w, float acc) {
#if __has_builtin(__builtin_amdgcn_fdot2)
  return __builtin_amdgcn_fdot2(__builtin_bit_cast(h2f16, packed), w, acc, false);
#else
  h2f16 a = __builtin_bit_cast(h2f16, packed);
  acc = fmaf((float)a.x, (float)w.x, acc);
  return fmaf((float)a.y, (float)w.y, acc);
#endif
}

// Alignment-preserving LDS swizzle on pair-index (keeps bits [1:0]).
__device__ __forceinline__ int swz(int p) { return p ^ (((p >> 5) & 7) << 2); }

template<int NSLOT>
__global__ __launch_bounds__(NTH, 2) void ctrnn_kernel(
    const float* __restrict__ x,        // [TIME, DIM]
    const float* __restrict__ W,        // [DIM, DIM]
    const float* __restrict__ bias,     // [DIM]
    const float* __restrict__ initial,  // [DIM]
    float* __restrict__ out,            // [TIME, DIM]
    uint32_t* __restrict__ actbuf,
    uint32_t* __restrict__ progress,
    uint32_t* __restrict__ xccmap)
{
  const int tid  = threadIdx.x;
  const int lane = tid & 63;
  const int wv   = tid >> 6;            // wave in block (0..7)

  // ---- phase 0: report this block's XCD ----
  if (tid == 0) {
    uint32_t xcc;
    asm volatile("s_getreg_b32 %0, hwreg(HW_REG_XCC_ID)" : "=s"(xcc));
    __hip_atomic_store(&xccmap[blockIdx.x], xcc,
                       __ATOMIC_RELAXED, __HIP_MEMORY_SCOPE_AGENT);
  }
  cooperative_groups::this_grid().sync();

  // ---- phase 1: deterministic election (bijective rank permutation):
  //      blocks on block-0's XCD first, then the rest. Exactly NWORK workers
  //      always; placement affects speed only, never correctness/liveness.
  __shared__ uint32_t s_map[NBLK];
  for (int i = tid; i < NBLK; i += NTH)
    s_map[i] = __hip_atomic_load(&xccmap[i], __ATOMIC_RELAXED, __HIP_MEMORY_SCOPE_AGENT);
  __syncthreads();
  const uint32_t target = s_map[0];
  int before = 0, total = 0, beforeN = 0;
  const int bid = blockIdx.x;
  for (int i = 0; i < NBLK; ++i) {
    const bool m = (s_map[i] == target);
    total += m;
    if (i < bid) { before += m; beforeN += !m; }
  }
  const bool mine = (s_map[bid] == target);
  const int rank = mine ? before : (total + beforeN);
  if (rank >= NWORK) return;            // 224 blocks exit; no further grid syncs
  const int wb = rank;

  __shared__ uint32_t lds[2][1024];     // packed fp16-pair acts, swizzled

  const int gwid = wb * WVB + wv;       // worker wave id 0..255
  const int row0 = gwid * RPW;

  // W fragment fp16x2: 8 rows x cols [lane*32, lane*32+32) = 128 VGPRs.
  h2f16 w2[RPW][16];
  #pragma unroll
  for (int m = 0; m < RPW; ++m) {
    const float* wr = W + (size_t)(row0 + m) * DIM + lane * 32;
    #pragma unroll
    for (int q = 0; q < 16; ++q)
      w2[m][q] = h2f16{(_Float16)wr[2*q], (_Float16)wr[2*q+1]};
  }

  // ---- batched x window: [t0, t0+16), 2 VGPRs/lane, all 64 lanes carry it.
  //      Lane (xq, xr) holds x[t0+xq][row0+xr] (xa) and x[t0+8+xq][row0+xr]
  //      (xb). Distribution at step t: one ds_bpermute from lane
  //      ((off&7)<<3)|xr. Refill every 16 steps with >=2 steps of slack.
  const int xq = lane >> 3, xr = lane & 7;
  float xa = x[(size_t)xq * DIM + row0 + xr];
  float xb = x[(size_t)(8 + xq) * DIM + row0 + xr];
  float xa2 = 0.f, xb2 = 0.f;
  int t0 = 0;

  // State: lanes 0..7 own rows row0..row0+7.
  float v = 0.f, bj = 0.f;
  if (lane < RPW) {
    const int j = row0 + lane;
    v  = initial[j];
    bj = bias[j];
    out[j] = v;
    const float a0 = 1.0f / (1.0f + __expf(-(v + bj)));
    __half h = __float2half_rn(a0);
    uint16_t hb; __builtin_memcpy(&hb, &h, 2);
    __hip_atomic_store(&actbuf[j], (1u << 16) | hb,
                       __ATOMIC_RELAXED, __HIP_MEMORY_SCOPE_AGENT);
  }

  // Staging geometry: wave wv owns entries [wv*256, wv*256+256);
  // lane's quad at entry e0 -> even pair index p0.
  const int e0 = wv * 256 + lane * 4;
  const int p0 = e0 >> 1;

  uint32_t prog_seen = 0;

  for (int t = 0; t < TIME_STEPS - 1; ++t) {
    const int b = t & 1;
    const int off = t - t0;
    const uint32_t needtag = (uint32_t)(t + 1);
    const uint32_t thresh  = needtag << 16;

    // ---- early-out tagged poll (sc1): only stale lanes reload ----
    const uint32_t* qsrc = actbuf + (size_t)(t & (NSLOT - 1)) * DIM + e0;
    u32x4 q;
    bool ok = false;
    do {
      if (!ok) {
        asm volatile("global_load_dwordx4 %0, %1, off sc1\n\t"
                     "s_waitcnt vmcnt(0)"
                     : "=&v"(q) : "v"(qsrc) : "memory");
        ok = umin32(umin32(q[0], q[1]), umin32(q[2], q[3])) >= thresh;
      }
    } while (!__all((int)ok));

    // ---- stage packed fp16 pairs into swizzled LDS (perm at stage time) ----
    {
      const uint32_t lo = __builtin_amdgcn_perm(q[1], q[0], 0x05040100u);
      const uint32_t hi = __builtin_amdgcn_perm(q[3], q[2], 0x05040100u);
      const int w0 = swz(p0);
      lds[b][w0]     = lo;
      lds[b][w0 + 1] = hi;
    }

    __syncthreads();  // slot t fully staged in lds[b]

    if (tid == 0)
      __hip_atomic_store(&progress[wb], needtag,
                         __ATOMIC_RELAXED, __HIP_MEMORY_SCOPE_AGENT);

    // ---- x window refill (once per 16 steps; >=2 steps before first use) ----
    if (off == 13) {
      const int ta = min(t0 + 16 + xq, TIME_STEPS - 1);
      const int tb = min(t0 + 24 + xq, TIME_STEPS - 1);
      xa2 = x[(size_t)ta * DIM + row0 + xr];
      xb2 = x[(size_t)tb * DIM + row0 + xr];
    }

    // ---- dot: 8 rows x 32 cols (pairs lane*16..+15), 4x ds_read_b128 ----
    float a0 = 0.f, a1 = 0.f, a2 = 0.f, a3 = 0.f;
    float a4 = 0.f, a5 = 0.f, a6 = 0.f, a7 = 0.f;
    #pragma unroll
    for (int j = 0; j < 4; ++j) {
      const u32x4 qq = *reinterpret_cast<const u32x4*>(&lds[b][swz(lane * 16 + 4 * j)]);
      #pragma unroll
      for (int i = 0; i < 4; ++i) {
        const uint32_t pr = qq[i];
        const int idx = 4 * j + i;
        a0 = dot2f(pr, w2[0][idx], a0);
        a1 = dot2f(pr, w2[1][idx], a1);
        a2 = dot2f(pr, w2[2][idx], a2);
        a3 = dot2f(pr, w2[3][idx], a3);
        a4 = dot2f(pr, w2[4][idx], a4);
        a5 = dot2f(pr, w2[5][idx], a5);
        a6 = dot2f(pr, w2[6][idx], a6);
        a7 = dot2f(pr, w2[7][idx], a7);
      }
    }

    // ---- merge-reduce: lane l ends with row (l&7) total ----
    const float t0r = a0 + __shfl_xor(a0, 1, 64);
    const float t1r = a1 + __shfl_xor(a1, 1, 64);
    const float t2r = a2 + __shfl_xor(a2, 1, 64);
    const float t3r = a3 + __shfl_xor(a3, 1, 64);
    const float t4r = a4 + __shfl_xor(a4, 1, 64);
    const float t5r = a5 + __shfl_xor(a5, 1, 64);
    const float t6r = a6 + __shfl_xor(a6, 1, 64);
    const float t7r = a7 + __shfl_xor(a7, 1, 64);
    float b0 = (lane & 1) ? t1r : t0r;
    float b1 = (lane & 1) ? t3r : t2r;
    float b2 = (lane & 1) ? t5r : t4r;
    float b3 = (lane & 1) ? t7r : t6r;
    b0 += __shfl_xor(b0, 2, 64);
    b1 += __shfl_xor(b1, 2, 64);
    b2 += __shfl_xor(b2, 2, 64);
    b3 += __shfl_xor(b3, 2, 64);
    float c0 = (lane & 2) ? b1 : b0;
    float c1 = (lane & 2) ? b3 : b2;
    c0 += __shfl_xor(c0, 4, 64);
    c1 += __shfl_xor(c1, 4, 64);
    float p = (lane & 4) ? c1 : c0;
    p += __shfl_xor(p, 8, 64);
    p += __shfl_xor(p, 16, 64);
    p += __shfl_xor(p, 32, 64);

    // ---- WAR gate: publish gen t+1 over slot (t+1)%NSLOT only after all
    //      worker blocks staged gen t+2-NSLOT. Fires ~every NSLOT-1 steps. ----
    if (t >= NSLOT - 1) {
      const uint32_t need = (uint32_t)(t + 2 - NSLOT);
      if (need > prog_seen) {
        for (;;) {
          uint32_t mn = __hip_atomic_load(&progress[lane & (NWORK - 1)],
                            __ATOMIC_RELAXED, __HIP_MEMORY_SCOPE_AGENT);
          uint32_t qv;
          qv = (uint32_t)__shfl_xor((int)mn, 1, 64);  mn = umin32(mn, qv);
          qv = (uint32_t)__shfl_xor((int)mn, 2, 64);  mn = umin32(mn, qv);
          qv = (uint32_t)__shfl_xor((int)mn, 4, 64);  mn = umin32(mn, qv);
          qv = (uint32_t)__shfl_xor((int)mn, 8, 64);  mn = umin32(mn, qv);
          qv = (uint32_t)__shfl_xor((int)mn, 16, 64); mn = umin32(mn, qv);
          if (mn >= need) { prog_seen = mn; break; }
          __builtin_amdgcn_s_sleep(1);
        }
      }
    }

    // ---- x for this step via one bpermute (window regs, no VMEM) ----
    const float xsrc = (off < 8) ? xa : xb;
    const float xvt  = __shfl(xsrc, ((off & 7) << 3) | xr, 64);

    // ---- state update: publish act FIRST, then out[] store ----
    if (lane < RPW) {
      v = 0.9f * v + 0.1f * (p + xvt);
      const float a = 1.0f / (1.0f + __expf(-(v + bj)));
      __half h = __float2half_rn(a);
      uint16_t hb; __builtin_memcpy(&hb, &h, 2);
      const uint32_t e = ((uint32_t)(t + 2) << 16) | hb;
      __hip_atomic_store(&actbuf[(size_t)((t + 1) & (NSLOT - 1)) * DIM + row0 + lane], e,
                         __ATOMIC_RELAXED, __HIP_MEMORY_SCOPE_AGENT);
      out[(size_t)(t + 1) * DIM + row0 + lane] = v;
    }

    // ---- window swap after last use ----
    if (off == 15) { t0 += 16; xa = xa2; xb = xb2; }
  }
}

extern "C" void kernel_launch(void* const* d_in, const int* in_sizes, int n_in,
                              void* d_out, int out_size, void* d_ws, size_t ws_size,
                              hipStream_t stream) {
  const float* x       = (const float*)d_in[0];
  const float* W       = (const float*)d_in[1];
  const float* bias    = (const float*)d_in[2];
  const float* initial = (const float*)d_in[3];
  float* out           = (float*)d_out;

  uint32_t* actbuf = (uint32_t*)d_ws;

  const size_t need8 = ((size_t)8 * DIM + NWORK + NBLK) * 4;
  void* kfun;
  size_t ringwords;
  if (ws_size >= need8) { kfun = (void*)ctrnn_kernel<8>; ringwords = (size_t)8 * DIM; }
  else                  { kfun = (void*)ctrnn_kernel<2>; ringwords = (size_t)2 * DIM; }

  uint32_t* progress = actbuf + ringwords;
  uint32_t* xccmap   = progress + NWORK;

  // Tags/progress are generation counters — clear every call (capture-safe).
  hipMemsetAsync(d_ws, 0, (ringwords + NWORK + NBLK) * 4, stream);

  void* args[] = { (void*)&x, (void*)&W, (void*)&bias, (void*)&initial,
                   (void*)&out, (void*)&actbuf, (void*)&progress, (void*)&xccmap };
  hipLaunchCooperativeKernel(kfun, dim3(NBLK), dim3(NTH), args, 0, stream);
}

// Round 14
// 9036.382 us; speedup vs baseline: 1.0588x; 1.0588x over previous
//
#include <hip/hip_runtime.h>
#include <hip/hip_fp16.h>
#include <hip/hip_cooperative_groups.h>
#include <stdint.h>

#define TIME_STEPS 4096
#define DIM        2048
#define NBLK       256    // grid (co-resident: 1 block/CU)
#define NTH        512    // 8 waves per block
#define NWORK      32     // worker blocks (one XCD's worth of CUs)
#define WVB        8      // waves per worker block
#define RPW        8      // rows per wave: 256 waves x 8 = 2048

typedef uint32_t u32x4 __attribute__((ext_vector_type(4)));
typedef _Float16 h2f16 __attribute__((ext_vector_type(2)));

// actbuf entry: u32 = (tag16<<16)|fp16bits(act); slot t%NSLOT holds gen t
// (tag=t+1). Validity: min over dwords >= tag<<16.
// r14: (1) 2-deep ping-pong poll — two loads in flight, vmcnt(1) retires the
// older -> fresh snapshot every ~half round trip instead of serial rounds;
// (2) row-per-lane dot layout -> 3-shuffle reduce + conflict-free LDS.
// d_ws: ring | progress[NWORK] | xccmap[NBLK]

__device__ __forceinline__ uint32_t umin32(uint32_t a, uint32_t b) { return a < b ? a : b; }

__device__ __forceinline__ float dot2f(uint32_t packed, h2f16 w, float acc) {
#if __has_builtin(__builtin_amdgcn_fdot2)
  return __builtin_amdgcn_fdot2(__builtin_bit_cast(h2f16, packed), w, acc, false);
#else
  h2f16 a = __builtin_bit_cast(h2f16, packed);
  acc = fmaf((float)a.x, (float)w.x, acc);
  return fmaf((float)a.y, (float)w.y, acc);
#endif
}

// Pair-index swizzle: xor bank bits [4:2] with producer-wave bits [9:7].
// Preserves low 2 bits (b128 contiguity); makes the reader's 8 col-groups
// (stride 128 pairs -> bank 0 unswizzled) land on 8 distinct bank quads.
__device__ __forceinline__ int swz2(int p) { return p ^ (((p >> 7) & 7) << 2); }

#define POLL_ISSUE(dst, src)                                       \
  asm volatile("global_load_dwordx4 %0, %1, off sc1"               \
               : "=&v"(dst) : "v"(src) : "memory")

template<int NSLOT>
__global__ __launch_bounds__(NTH, 2) void ctrnn_kernel(
    const float* __restrict__ x,        // [TIME, DIM]
    const float* __restrict__ W,        // [DIM, DIM]
    const float* __restrict__ bias,     // [DIM]
    const float* __restrict__ initial,  // [DIM]
    float* __restrict__ out,            // [TIME, DIM]
    uint32_t* __restrict__ actbuf,
    uint32_t* __restrict__ progress,
    uint32_t* __restrict__ xccmap)
{
  const int tid  = threadIdx.x;
  const int lane = tid & 63;
  const int wv   = tid >> 6;            // wave in block (0..7)

  // ---- phase 0: report this block's XCD ----
  if (tid == 0) {
    uint32_t xcc;
    asm volatile("s_getreg_b32 %0, hwreg(HW_REG_XCC_ID)" : "=s"(xcc));
    __hip_atomic_store(&xccmap[blockIdx.x], xcc,
                       __ATOMIC_RELAXED, __HIP_MEMORY_SCOPE_AGENT);
  }
  cooperative_groups::this_grid().sync();

  // ---- phase 1: deterministic election (bijective rank permutation) ----
  __shared__ uint32_t s_map[NBLK];
  for (int i = tid; i < NBLK; i += NTH)
    s_map[i] = __hip_atomic_load(&xccmap[i], __ATOMIC_RELAXED, __HIP_MEMORY_SCOPE_AGENT);
  __syncthreads();
  const uint32_t target = s_map[0];
  int before = 0, total = 0, beforeN = 0;
  const int bid = blockIdx.x;
  for (int i = 0; i < NBLK; ++i) {
    const bool m = (s_map[i] == target);
    total += m;
    if (i < bid) { before += m; beforeN += !m; }
  }
  const bool mine = (s_map[bid] == target);
  const int rank = mine ? before : (total + beforeN);
  if (rank >= NWORK) return;            // 224 blocks exit; no further grid syncs
  const int wb = rank;

  __shared__ uint32_t lds[2][1024];     // packed fp16-pair acts, swz2 layout

  const int gwid = wb * WVB + wv;       // worker wave id 0..255
  const int row0 = gwid * RPW;

  // Row-per-lane layout: lane = (c<<3)|r; row = row0+r, cols [c*256,(c+1)*256).
  const int r_ = lane & 7;
  const int c_ = lane >> 3;

  // W fragment fp16x2: 1 row x 256 cols = 128 VGPRs.
  h2f16 w2[128];
  {
    const float* wr = W + (size_t)(row0 + r_) * DIM + c_ * 256;
    #pragma unroll
    for (int q = 0; q < 128; ++q)
      w2[q] = h2f16{(_Float16)wr[2*q], (_Float16)wr[2*q+1]};
  }

  // ---- batched x window: [t0, t0+16), 2 VGPRs/lane (see r13) ----
  const int xq = lane >> 3, xr = lane & 7;
  float xa = x[(size_t)xq * DIM + row0 + xr];
  float xb = x[(size_t)(8 + xq) * DIM + row0 + xr];
  float xa2 = 0.f, xb2 = 0.f;
  int t0 = 0;

  // State: lanes 0..7 own rows row0..row0+7.
  float v = 0.f, bj = 0.f;
  if (lane < RPW) {
    const int j = row0 + lane;
    v  = initial[j];
    bj = bias[j];
    out[j] = v;
    const float a0 = 1.0f / (1.0f + __expf(-(v + bj)));
    __half h = __float2half_rn(a0);
    uint16_t hb; __builtin_memcpy(&hb, &h, 2);
    __hip_atomic_store(&actbuf[j], (1u << 16) | hb,
                       __ATOMIC_RELAXED, __HIP_MEMORY_SCOPE_AGENT);
  }

  // Staging geometry: wave wv owns entries [wv*256, +256); lane's quad at e0.
  const int e0 = wv * 256 + lane * 4;
  const int p0 = e0 >> 1;              // even pair index

  uint32_t prog_seen = 0;

  for (int t = 0; t < TIME_STEPS - 1; ++t) {
    const int b = t & 1;
    const int off = t - t0;
    const uint32_t needtag = (uint32_t)(t + 1);
    const uint32_t thresh  = needtag << 16;

    // ---- 2-deep ping-pong poll (sc1); per-lane early exit ----
    const uint32_t* qsrc = actbuf + (size_t)(t & (NSLOT - 1)) * DIM + e0;
    u32x4 qa, qb, q;
    POLL_ISSUE(qa, qsrc);
    POLL_ISSUE(qb, qsrc);
    for (;;) {
      asm volatile("s_waitcnt vmcnt(1)" ::: "memory");   // qa landed
      __builtin_amdgcn_sched_barrier(0);
      if (umin32(umin32(qa[0], qa[1]), umin32(qa[2], qa[3])) >= thresh) { q = qa; break; }
      POLL_ISSUE(qa, qsrc);
      asm volatile("s_waitcnt vmcnt(1)" ::: "memory");   // qb landed
      __builtin_amdgcn_sched_barrier(0);
      if (umin32(umin32(qb[0], qb[1]), umin32(qb[2], qb[3])) >= thresh) { q = qb; break; }
      POLL_ISSUE(qb, qsrc);
    }
    asm volatile("s_waitcnt vmcnt(0)" ::: "memory");     // retire strays (reg reuse)
    __builtin_amdgcn_sched_barrier(0);

    // ---- stage packed fp16 pairs into swz2 LDS ----
    {
      const uint32_t lo = __builtin_amdgcn_perm(q[1], q[0], 0x05040100u);
      const uint32_t hi = __builtin_amdgcn_perm(q[3], q[2], 0x05040100u);
      const int w0 = swz2(p0);
      lds[b][w0]     = lo;
      lds[b][w0 + 1] = hi;
    }

    __syncthreads();  // slot t fully staged in lds[b]

    if (tid == 0)
      __hip_atomic_store(&progress[wb], needtag,
                         __ATOMIC_RELAXED, __HIP_MEMORY_SCOPE_AGENT);

    // ---- x window refill (once per 16 steps) ----
    if (off == 13) {
      const int ta = min(t0 + 16 + xq, TIME_STEPS - 1);
      const int tb = min(t0 + 24 + xq, TIME_STEPS - 1);
      xa2 = x[(size_t)ta * DIM + row0 + xr];
      xb2 = x[(size_t)tb * DIM + row0 + xr];
    }

    // ---- dot: row r_ over cols [c_*256, +256): 32 b128 reads (8-lane
    //      broadcast, conflict-free), 128 dot2 into 4 chains ----
    float ac0 = 0.f, ac1 = 0.f, ac2 = 0.f, ac3 = 0.f;
    const int cbase = c_ * 128;
    #pragma unroll
    for (int j = 0; j < 32; ++j) {
      const u32x4 qq = *reinterpret_cast<const u32x4*>(&lds[b][swz2(cbase + 4 * j)]);
      ac0 = dot2f(qq[0], w2[4*j+0], ac0);
      ac1 = dot2f(qq[1], w2[4*j+1], ac1);
      ac2 = dot2f(qq[2], w2[4*j+2], ac2);
      ac3 = dot2f(qq[3], w2[4*j+3], ac3);
    }
    float p = (ac0 + ac1) + (ac2 + ac3);
    // fold over c (bits 3,4,5): lane l ends with row (l&7) total
    p += __shfl_xor(p, 8, 64);
    p += __shfl_xor(p, 16, 64);
    p += __shfl_xor(p, 32, 64);

    // ---- WAR gate: fires ~every NSLOT-1 steps ----
    if (t >= NSLOT - 1) {
      const uint32_t need = (uint32_t)(t + 2 - NSLOT);
      if (need > prog_seen) {
        for (;;) {
          uint32_t mn = __hip_atomic_load(&progress[lane & (NWORK - 1)],
                            __ATOMIC_RELAXED, __HIP_MEMORY_SCOPE_AGENT);
          uint32_t qv;
          qv = (uint32_t)__shfl_xor((int)mn, 1, 64);  mn = umin32(mn, qv);
          qv = (uint32_t)__shfl_xor((int)mn, 2, 64);  mn = umin32(mn, qv);
          qv = (uint32_t)__shfl_xor((int)mn, 4, 64);  mn = umin32(mn, qv);
          qv = (uint32_t)__shfl_xor((int)mn, 8, 64);  mn = umin32(mn, qv);
          qv = (uint32_t)__shfl_xor((int)mn, 16, 64); mn = umin32(mn, qv);
          if (mn >= need) { prog_seen = mn; break; }
          __builtin_amdgcn_s_sleep(1);
        }
      }
    }

    // ---- x for this step via one bpermute (window regs, no VMEM) ----
    const float xsrc = (off < 8) ? xa : xb;
    const float xvt  = __shfl(xsrc, ((off & 7) << 3) | xr, 64);

    // ---- state update: publish act FIRST, then out[] store ----
    if (lane < RPW) {
      v = 0.9f * v + 0.1f * (p + xvt);
      const float a = 1.0f / (1.0f + __expf(-(v + bj)));
      __half h = __float2half_rn(a);
      uint16_t hb; __builtin_memcpy(&hb, &h, 2);
      const uint32_t e = ((uint32_t)(t + 2) << 16) | hb;
      __hip_atomic_store(&actbuf[(size_t)((t + 1) & (NSLOT - 1)) * DIM + row0 + lane], e,
                         __ATOMIC_RELAXED, __HIP_MEMORY_SCOPE_AGENT);
      out[(size_t)(t + 1) * DIM + row0 + lane] = v;
    }

    // ---- window swap after last use ----
    if (off == 15) { t0 += 16; xa = xa2; xb = xb2; }
  }
}

extern "C" void kernel_launch(void* const* d_in, const int* in_sizes, int n_in,
                              void* d_out, int out_size, void* d_ws, size_t ws_size,
                              hipStream_t stream) {
  const float* x       = (const float*)d_in[0];
  const float* W       = (const float*)d_in[1];
  const float* bias    = (const float*)d_in[2];
  const float* initial = (const float*)d_in[3];
  float* out           = (float*)d_out;

  uint32_t* actbuf = (uint32_t*)d_ws;

  const size_t need8 = ((size_t)8 * DIM + NWORK + NBLK) * 4;
  void* kfun;
  size_t ringwords;
  if (ws_size >= need8) { kfun = (void*)ctrnn_kernel<8>; ringwords = (size_t)8 * DIM; }
  else                  { kfun = (void*)ctrnn_kernel<2>; ringwords = (size_t)2 * DIM; }

  uint32_t* progress = actbuf + ringwords;
  uint32_t* xccmap   = progress + NWORK;

  // Tags/progress are generation counters — clear every call (capture-safe).
  hipMemsetAsync(d_ws, 0, (ringwords + NWORK + NBLK) * 4, stream);

  void* args[] = { (void*)&x, (void*)&W, (void*)&bias, (void*)&initial,
                   (void*)&out, (void*)&actbuf, (void*)&progress, (void*)&xccmap };
  hipLaunchCooperativeKernel(kfun, dim3(NBLK), dim3(NTH), args, 0, stream);
}